// Round 1
// baseline (3026.932 us; speedup 1.0000x reference)
//
#include <hip/hip_runtime.h>
#include <hip/hip_bf16.h>

#define EPSV 1e-5f
#define SLOPE 0.1f

// ---------------- degree ----------------
__global__ __launch_bounds__(256) void k_count(const int* __restrict__ col,
                                               unsigned* __restrict__ cnt, int E) {
    int e = blockIdx.x * 256 + threadIdx.x;
    if (e < E) atomicAdd(&cnt[col[e]], 1u);
}

__global__ __launch_bounds__(256) void k_dinv(const unsigned* __restrict__ cnt,
                                              float* __restrict__ dinv, int N) {
    int n = blockIdx.x * 256 + threadIdx.x;
    if (n < N) dinv[n] = rsqrtf((float)cnt[n] + 2.0f);
}

// ---------------- GEMM: Y[N,128] = X[N,128] @ W[128,128] (+bias) ----------------
__global__ __launch_bounds__(256) void k_gemm(const float* __restrict__ X,
                                              const float* __restrict__ W,
                                              const float* __restrict__ bias,
                                              float* __restrict__ Y, int N) {
    __shared__ float xs[64][132];
    const int tid = threadIdx.x;
    const int base = blockIdx.x * 64;
    // stage 64 rows x 128 cols
    for (int i = tid; i < 2048; i += 256) {
        int r = i >> 5, c4 = i & 31;
        int row = base + r; if (row >= N) row = N - 1;
        float4 v = ((const float4*)(X + (size_t)row * 128))[c4];
        *(float4*)(&xs[r][c4 * 4]) = v;
    }
    __syncthreads();
    const int c0 = (tid & 31) * 4;
    const int rg = tid >> 5;  // 0..7
    float acc[8][4];
#pragma unroll
    for (int i = 0; i < 8; i++) { acc[i][0] = acc[i][1] = acc[i][2] = acc[i][3] = 0.f; }
    for (int k = 0; k < 128; k += 4) {
        float4 w0 = *(const float4*)(W + (size_t)(k + 0) * 128 + c0);
        float4 w1 = *(const float4*)(W + (size_t)(k + 1) * 128 + c0);
        float4 w2 = *(const float4*)(W + (size_t)(k + 2) * 128 + c0);
        float4 w3 = *(const float4*)(W + (size_t)(k + 3) * 128 + c0);
#pragma unroll
        for (int i = 0; i < 8; i++) {
            float4 a = *(const float4*)(&xs[rg + 8 * i][k]);
            acc[i][0] = fmaf(a.x, w0.x, fmaf(a.y, w1.x, fmaf(a.z, w2.x, fmaf(a.w, w3.x, acc[i][0]))));
            acc[i][1] = fmaf(a.x, w0.y, fmaf(a.y, w1.y, fmaf(a.z, w2.y, fmaf(a.w, w3.y, acc[i][1]))));
            acc[i][2] = fmaf(a.x, w0.z, fmaf(a.y, w1.z, fmaf(a.z, w2.z, fmaf(a.w, w3.z, acc[i][2]))));
            acc[i][3] = fmaf(a.x, w0.w, fmaf(a.y, w1.w, fmaf(a.z, w2.w, fmaf(a.w, w3.w, acc[i][3]))));
        }
    }
#pragma unroll
    for (int i = 0; i < 8; i++) {
        int row = base + rg + 8 * i;
        if (row < N) {
            float4 o = make_float4(acc[i][0], acc[i][1], acc[i][2], acc[i][3]);
            if (bias) { o.x += bias[c0]; o.y += bias[c0 + 1]; o.z += bias[c0 + 2]; o.w += bias[c0 + 3]; }
            ((float4*)(Y + (size_t)row * 128))[tid & 31] = o;
        }
    }
}

// ---------------- edge aggregation: agg[col] += dinv[row]*dinv[col]*xw[row] ----------------
__global__ __launch_bounds__(256) void k_agg(const float* __restrict__ xw,
                                             const int* __restrict__ row,
                                             const int* __restrict__ col,
                                             const float* __restrict__ dinv,
                                             float* __restrict__ agg, int E) {
    int gid = blockIdx.x * 256 + threadIdx.x;
    int e = gid >> 5;
    if (e >= E) return;
    int q = gid & 31;
    int r = row[e], c = col[e];
    float nrm = dinv[r] * dinv[c];
    float4 v = ((const float4*)(xw + (size_t)r * 128))[q];
    float* dst = agg + (size_t)c * 128 + q * 4;
    atomicAdd(dst + 0, nrm * v.x);
    atomicAdd(dst + 1, nrm * v.y);
    atomicAdd(dst + 2, nrm * v.z);
    atomicAdd(dst + 3, nrm * v.w);
}

// ---------------- self-loop + bias + BN stats (h updated in place) ----------------
__global__ __launch_bounds__(256) void k_finalize(float* __restrict__ h,
                                                  const float* __restrict__ xw,
                                                  const float* __restrict__ dinv,
                                                  const float* __restrict__ bias,
                                                  float* __restrict__ sums, int N) {
    const int f = threadIdx.x & 127;
    const int rowInBlk = threadIdx.x >> 7;  // 0..1
    float s = 0.f, s2 = 0.f;
    const float b = bias[f];
    for (int n = blockIdx.x * 2 + rowInBlk; n < N; n += gridDim.x * 2) {
        float d = dinv[n];
        size_t idx = (size_t)n * 128 + f;
        float v = h[idx] + 2.f * d * d * xw[idx] + b;
        h[idx] = v;
        s += v; s2 += v * v;
    }
    __shared__ float ls[256], ls2[256];
    ls[threadIdx.x] = s; ls2[threadIdx.x] = s2;
    __syncthreads();
    if (threadIdx.x < 128) {
        s = ls[threadIdx.x] + ls[threadIdx.x + 128];
        s2 = ls2[threadIdx.x] + ls2[threadIdx.x + 128];
        atomicAdd(&sums[f], s);
        atomicAdd(&sums[128 + f], s2);
    }
}

// ---------------- BN apply + leaky relu (in place) ----------------
__global__ __launch_bounds__(256) void k_bn(float* __restrict__ h,
                                            const float* __restrict__ sums,
                                            const float* __restrict__ w,
                                            const float* __restrict__ b,
                                            float invN, int total) {
    const int f = threadIdx.x & 127;
    float mu = sums[f] * invN;
    float var = sums[128 + f] * invN - mu * mu;
    float scale = rsqrtf(var + EPSV) * w[f];
    float bias = b[f] - mu * scale;
    for (int i = blockIdx.x * 256 + threadIdx.x; i < total; i += gridDim.x * 256) {
        float v = fmaf(h[i], scale, bias);
        h[i] = v > 0.f ? v : SLOPE * v;
    }
}

// ---------------- pooling ----------------
__global__ __launch_bounds__(256) void k_pool_init(unsigned* __restrict__ p, int total) {
    int i = blockIdx.x * 256 + threadIdx.x;
    if (i < total) p[i] = 0x007FFFFFu;  // encoded -inf
}

__global__ __launch_bounds__(256) void k_pool(const float* __restrict__ h,
                                              const int* __restrict__ batch,
                                              unsigned* __restrict__ pooled, long long total) {
    long long i = (long long)blockIdx.x * 256 + threadIdx.x;
    if (i >= total) return;
    int n = (int)(i >> 7), f = (int)(i & 127);
    unsigned u = __float_as_uint(h[i]);
    u = (u & 0x80000000u) ? ~u : (u | 0x80000000u);
    atomicMax(&pooled[(size_t)batch[n] * 128 + f], u);
}

__global__ __launch_bounds__(256) void k_decode(unsigned* __restrict__ p, int total) {
    int i = blockIdx.x * 256 + threadIdx.x;
    if (i >= total) return;
    unsigned u = p[i];
    float v;
    if (u == 0x007FFFFFu) v = 0.f;  // empty graph (-inf) -> 0
    else if (u & 0x80000000u) v = __uint_as_float(u & 0x7FFFFFFFu);
    else v = __uint_as_float(~u);
    p[i] = __float_as_uint(v);
}

extern "C" void kernel_launch(void* const* d_in, const int* in_sizes, int n_in,
                              void* d_out, int out_size, void* d_ws, size_t ws_size,
                              hipStream_t stream) {
    const float* x     = (const float*)d_in[0];
    const int*   ei    = (const int*)d_in[1];
    const int*   batch = (const int*)d_in[2];
    const float* W1    = (const float*)d_in[3];
    const float* b1    = (const float*)d_in[4];
    const float* bn1w  = (const float*)d_in[5];
    const float* bn1b  = (const float*)d_in[6];
    const float* W2    = (const float*)d_in[7];
    const float* b2    = (const float*)d_in[8];
    const float* bn2w  = (const float*)d_in[9];
    const float* bn2b  = (const float*)d_in[10];
    const float* Wf    = (const float*)d_in[11];
    const float* bf    = (const float*)d_in[12];

    const int N = in_sizes[0] / 128;
    const int E = in_sizes[1] / 2;
    const int G = out_size / 128;
    const int* rowp = ei;
    const int* colp = ei + E;
    float* out = (float*)d_out;

    char* w = (char*)d_ws;
    float*    bufA   = (float*)w;    w += (size_t)N * 128 * 4;
    float*    bufB   = (float*)w;    w += (size_t)N * 128 * 4;
    float*    dinv   = (float*)w;    w += (size_t)N * 4;
    unsigned* cnt    = (unsigned*)w; w += (size_t)N * 4;
    float*    sums   = (float*)w;    w += 256 * 4;
    unsigned* pooled = (unsigned*)w; w += (size_t)G * 128 * 4;

    // degrees
    hipMemsetAsync(cnt, 0, (size_t)N * 4, stream);
    k_count<<<(E + 255) / 256, 256, 0, stream>>>(colp, cnt, E);
    k_dinv<<<(N + 255) / 256, 256, 0, stream>>>(cnt, dinv, N);

    const int aggBlocks = (int)(((long long)E * 32 + 255) / 256);
    const int poolBlocks = (int)(((long long)N * 128 + 255) / 256);

    // ---- layer 1 ----
    k_gemm<<<(N + 63) / 64, 256, 0, stream>>>(x, W1, nullptr, bufA, N);
    hipMemsetAsync(bufB, 0, (size_t)N * 128 * 4, stream);
    k_agg<<<aggBlocks, 256, 0, stream>>>(bufA, rowp, colp, dinv, bufB, E);
    hipMemsetAsync(sums, 0, 256 * 4, stream);
    k_finalize<<<1024, 256, 0, stream>>>(bufB, bufA, dinv, b1, sums, N);
    k_bn<<<2048, 256, 0, stream>>>(bufB, sums, bn1w, bn1b, 1.0f / N, N * 128);

    // ---- layer 2 ----
    k_gemm<<<(N + 63) / 64, 256, 0, stream>>>(bufB, W2, nullptr, bufA, N);
    hipMemsetAsync(bufB, 0, (size_t)N * 128 * 4, stream);
    k_agg<<<aggBlocks, 256, 0, stream>>>(bufA, rowp, colp, dinv, bufB, E);
    hipMemsetAsync(sums, 0, 256 * 4, stream);
    k_finalize<<<1024, 256, 0, stream>>>(bufB, bufA, dinv, b2, sums, N);
    k_bn<<<2048, 256, 0, stream>>>(bufB, sums, bn2w, bn2b, 1.0f / N, N * 128);

    // ---- pooling ----
    k_pool_init<<<(G * 128 + 255) / 256, 256, 0, stream>>>(pooled, G * 128);
    k_pool<<<poolBlocks, 256, 0, stream>>>(bufB, batch, pooled, (long long)N * 128);
    k_decode<<<(G * 128 + 255) / 256, 256, 0, stream>>>(pooled, G * 128);

    // ---- final GEMM ----
    k_gemm<<<(G + 63) / 64, 256, 0, stream>>>((const float*)pooled, Wf, bf, out, G);
}

// Round 2
// 542.858 us; speedup vs baseline: 5.5759x; 5.5759x over previous
//
#include <hip/hip_runtime.h>
#include <hip/hip_bf16.h>

#define EPSV 1e-5f
#define SLOPE 0.1f

// ---------------- degree ----------------
__global__ __launch_bounds__(256) void k_count(const int* __restrict__ col,
                                               unsigned* __restrict__ cnt, int E) {
    int e = blockIdx.x * 256 + threadIdx.x;
    if (e < E) atomicAdd(&cnt[col[e]], 1u);
}

__global__ __launch_bounds__(256) void k_dinv(const unsigned* __restrict__ cnt,
                                              float* __restrict__ dinv, int N) {
    int n = blockIdx.x * 256 + threadIdx.x;
    if (n < N) dinv[n] = rsqrtf((float)cnt[n] + 2.0f);
}

// ---------------- exclusive scan (3 kernels, 1024-elem chunks) ----------------
__global__ __launch_bounds__(256) void k_chunk_sum(const unsigned* __restrict__ cnt, int N,
                                                   unsigned* __restrict__ bsum) {
    __shared__ unsigned ls[256];
    int base = blockIdx.x * 1024;
    unsigned s = 0;
    for (int i = threadIdx.x; i < 1024; i += 256) {
        int idx = base + i;
        if (idx < N) s += cnt[idx];
    }
    ls[threadIdx.x] = s;
    __syncthreads();
    for (int st = 128; st > 0; st >>= 1) {
        if (threadIdx.x < st) ls[threadIdx.x] += ls[threadIdx.x + st];
        __syncthreads();
    }
    if (threadIdx.x == 0) bsum[blockIdx.x] = ls[0];
}

__global__ void k_scan_bsum(unsigned* __restrict__ bsum, int nb) {
    if (threadIdx.x == 0 && blockIdx.x == 0) {
        unsigned acc = 0;
        for (int i = 0; i < nb; i++) { unsigned v = bsum[i]; bsum[i] = acc; acc += v; }
    }
}

__global__ __launch_bounds__(256) void k_scan_chunks(const unsigned* __restrict__ cnt, int N,
                                                     const unsigned* __restrict__ bsum,
                                                     int* __restrict__ off, int E) {
    __shared__ unsigned ls[256];
    int base = blockIdx.x * 1024;
    unsigned v[4];
    unsigned s = 0;
#pragma unroll
    for (int j = 0; j < 4; j++) {
        int idx = base + threadIdx.x * 4 + j;
        v[j] = (idx < N) ? cnt[idx] : 0u;
        s += v[j];
    }
    ls[threadIdx.x] = s;
    __syncthreads();
    if (threadIdx.x == 0) {
        unsigned acc = bsum[blockIdx.x];
        for (int i = 0; i < 256; i++) { unsigned t = ls[i]; ls[i] = acc; acc += t; }
    }
    __syncthreads();
    unsigned acc = ls[threadIdx.x];
#pragma unroll
    for (int j = 0; j < 4; j++) {
        int idx = base + threadIdx.x * 4 + j;
        if (idx < N) off[idx] = (int)acc;
        acc += v[j];
    }
    if (base + threadIdx.x * 4 <= N - 1 && N - 1 < base + threadIdx.x * 4 + 4) off[N] = E;
}

// ---------------- counting-sort placement: srow/snorm grouped by col ----------------
__global__ __launch_bounds__(256) void k_place(const int* __restrict__ row,
                                               const int* __restrict__ col,
                                               const float* __restrict__ dinv,
                                               int* __restrict__ cursor,
                                               int* __restrict__ srow,
                                               float* __restrict__ snorm, int E) {
    int e = blockIdx.x * 256 + threadIdx.x;
    if (e >= E) return;
    int r = row[e], c = col[e];
    int pos = atomicAdd(&cursor[c], 1);
    srow[pos] = r;
    snorm[pos] = dinv[r] * dinv[c];
}

// ---------------- GEMM: Y[N,128] = X[N,128] @ W[128,128] (+bias) ----------------
__global__ __launch_bounds__(256) void k_gemm(const float* __restrict__ X,
                                              const float* __restrict__ W,
                                              const float* __restrict__ bias,
                                              float* __restrict__ Y, int N) {
    __shared__ float xs[64][132];
    const int tid = threadIdx.x;
    const int base = blockIdx.x * 64;
    for (int i = tid; i < 2048; i += 256) {
        int r = i >> 5, c4 = i & 31;
        int row = base + r; if (row >= N) row = N - 1;
        float4 v = ((const float4*)(X + (size_t)row * 128))[c4];
        *(float4*)(&xs[r][c4 * 4]) = v;
    }
    __syncthreads();
    const int c0 = (tid & 31) * 4;
    const int rg = tid >> 5;
    float acc[8][4];
#pragma unroll
    for (int i = 0; i < 8; i++) { acc[i][0] = acc[i][1] = acc[i][2] = acc[i][3] = 0.f; }
    for (int k = 0; k < 128; k += 4) {
        float4 w0 = *(const float4*)(W + (size_t)(k + 0) * 128 + c0);
        float4 w1 = *(const float4*)(W + (size_t)(k + 1) * 128 + c0);
        float4 w2 = *(const float4*)(W + (size_t)(k + 2) * 128 + c0);
        float4 w3 = *(const float4*)(W + (size_t)(k + 3) * 128 + c0);
#pragma unroll
        for (int i = 0; i < 8; i++) {
            float4 a = *(const float4*)(&xs[rg + 8 * i][k]);
            acc[i][0] = fmaf(a.x, w0.x, fmaf(a.y, w1.x, fmaf(a.z, w2.x, fmaf(a.w, w3.x, acc[i][0]))));
            acc[i][1] = fmaf(a.x, w0.y, fmaf(a.y, w1.y, fmaf(a.z, w2.y, fmaf(a.w, w3.y, acc[i][1]))));
            acc[i][2] = fmaf(a.x, w0.z, fmaf(a.y, w1.z, fmaf(a.z, w2.z, fmaf(a.w, w3.z, acc[i][2]))));
            acc[i][3] = fmaf(a.x, w0.w, fmaf(a.y, w1.w, fmaf(a.z, w2.w, fmaf(a.w, w3.w, acc[i][3]))));
        }
    }
#pragma unroll
    for (int i = 0; i < 8; i++) {
        int row = base + rg + 8 * i;
        if (row < N) {
            float4 o = make_float4(acc[i][0], acc[i][1], acc[i][2], acc[i][3]);
            if (bias) { o.x += bias[c0]; o.y += bias[c0 + 1]; o.z += bias[c0 + 2]; o.w += bias[c0 + 3]; }
            ((float4*)(Y + (size_t)row * 128))[tid & 31] = o;
        }
    }
}

// ---------------- CSR aggregation (gather) + self-loop + bias + BN stats ----------------
// one wave per node; lane q of each 32-lane half covers features 4q..4q+3
__global__ __launch_bounds__(256) void k_agg2(const float* __restrict__ xw,
                                              const int* __restrict__ off,
                                              const int* __restrict__ srow,
                                              const float* __restrict__ snorm,
                                              const float* __restrict__ dinv,
                                              const float* __restrict__ bias,
                                              float* __restrict__ h,
                                              float* __restrict__ sums, int N) {
    __shared__ float ls1[128], ls2[128];
    const int tid = threadIdx.x;
    if (tid < 128) { ls1[tid] = 0.f; ls2[tid] = 0.f; }
    __syncthreads();

    const int lane = tid & 63;
    const int q = lane & 31;
    const int half = lane >> 5;
    const int waveG = blockIdx.x * 4 + (tid >> 6);
    const int nWaves = gridDim.x * 4;
    const float4* xw4 = (const float4*)xw;

    float st1[4] = {0.f, 0.f, 0.f, 0.f};
    float st2[4] = {0.f, 0.f, 0.f, 0.f};
    const float b = bias[q * 4 + 0];  // placeholder; load full float4 below
    float4 b4 = ((const float4*)bias)[q];
    (void)b;

    for (int n = waveG; n < N; n += nWaves) {
        int s = off[n], e = off[n + 1];
        float4 a = make_float4(0.f, 0.f, 0.f, 0.f);
        for (int i = s + half; i < e; i += 2) {
            int r = srow[i];
            float nm = snorm[i];
            float4 v = xw4[(size_t)r * 32 + q];
            a.x = fmaf(nm, v.x, a.x);
            a.y = fmaf(nm, v.y, a.y);
            a.z = fmaf(nm, v.z, a.z);
            a.w = fmaf(nm, v.w, a.w);
        }
        // combine the two 32-lane halves
        a.x += __shfl_xor(a.x, 32);
        a.y += __shfl_xor(a.y, 32);
        a.z += __shfl_xor(a.z, 32);
        a.w += __shfl_xor(a.w, 32);
        if (half == 0) {
            float dc = dinv[n];
            float sl = 2.f * dc * dc;
            float4 x4 = xw4[(size_t)n * 32 + q];
            float4 o;
            o.x = a.x + sl * x4.x + b4.x;
            o.y = a.y + sl * x4.y + b4.y;
            o.z = a.z + sl * x4.z + b4.z;
            o.w = a.w + sl * x4.w + b4.w;
            ((float4*)h)[(size_t)n * 32 + q] = o;
            st1[0] += o.x; st1[1] += o.y; st1[2] += o.z; st1[3] += o.w;
            st2[0] += o.x * o.x; st2[1] += o.y * o.y; st2[2] += o.z * o.z; st2[3] += o.w * o.w;
        }
    }
    if (half == 0) {
#pragma unroll
        for (int j = 0; j < 4; j++) {
            atomicAdd(&ls1[q * 4 + j], st1[j]);
            atomicAdd(&ls2[q * 4 + j], st2[j]);
        }
    }
    __syncthreads();
    if (tid < 128) {
        atomicAdd(&sums[tid], ls1[tid]);
        atomicAdd(&sums[128 + tid], ls2[tid]);
    }
}

// ---------------- BN apply + leaky relu (in place) ----------------
__global__ __launch_bounds__(256) void k_bn(float* __restrict__ h,
                                            const float* __restrict__ sums,
                                            const float* __restrict__ w,
                                            const float* __restrict__ b,
                                            float invN, int total) {
    const int f = threadIdx.x & 127;
    float mu = sums[f] * invN;
    float var = sums[128 + f] * invN - mu * mu;
    float scale = rsqrtf(var + EPSV) * w[f];
    float bias = b[f] - mu * scale;
    for (int i = blockIdx.x * 256 + threadIdx.x; i < total; i += gridDim.x * 256) {
        float v = fmaf(h[i], scale, bias);
        h[i] = v > 0.f ? v : SLOPE * v;
    }
}

// ---------------- pooling (batch is sorted -> register-accumulated segments) ----------------
__global__ __launch_bounds__(256) void k_pool_init(unsigned* __restrict__ p, int total) {
    int i = blockIdx.x * 256 + threadIdx.x;
    if (i < total) p[i] = 0x007FFFFFu;  // encoded -inf
}

__device__ inline unsigned enc_f(float x) {
    unsigned u = __float_as_uint(x);
    return (u & 0x80000000u) ? ~u : (u | 0x80000000u);
}

__global__ __launch_bounds__(256) void k_pool2(const float* __restrict__ h,
                                               const int* __restrict__ batch,
                                               unsigned* __restrict__ pooled, int N) {
    const int f = threadIdx.x & 127;
    const int half = threadIdx.x >> 7;
    const int base = blockIdx.x * 128;
    const int end = min(base + 128, N);
    float m = -__builtin_inff();
    int g = -1;
    for (int n = base + half; n < end; n += 2) {
        int bg = batch[n];
        if (bg != g) {
            if (g >= 0) atomicMax(&pooled[(size_t)g * 128 + f], enc_f(m));
            g = bg;
            m = -__builtin_inff();
        }
        m = fmaxf(m, h[(size_t)n * 128 + f]);
    }
    if (g >= 0) atomicMax(&pooled[(size_t)g * 128 + f], enc_f(m));
}

__global__ __launch_bounds__(256) void k_decode(unsigned* __restrict__ p, int total) {
    int i = blockIdx.x * 256 + threadIdx.x;
    if (i >= total) return;
    unsigned u = p[i];
    float v;
    if (u == 0x007FFFFFu) v = 0.f;  // empty graph (-inf) -> 0
    else if (u & 0x80000000u) v = __uint_as_float(u & 0x7FFFFFFFu);
    else v = __uint_as_float(~u);
    p[i] = __float_as_uint(v);
}

extern "C" void kernel_launch(void* const* d_in, const int* in_sizes, int n_in,
                              void* d_out, int out_size, void* d_ws, size_t ws_size,
                              hipStream_t stream) {
    const float* x     = (const float*)d_in[0];
    const int*   ei    = (const int*)d_in[1];
    const int*   batch = (const int*)d_in[2];
    const float* W1    = (const float*)d_in[3];
    const float* b1    = (const float*)d_in[4];
    const float* bn1w  = (const float*)d_in[5];
    const float* bn1b  = (const float*)d_in[6];
    const float* W2    = (const float*)d_in[7];
    const float* b2    = (const float*)d_in[8];
    const float* bn2w  = (const float*)d_in[9];
    const float* bn2b  = (const float*)d_in[10];
    const float* Wf    = (const float*)d_in[11];
    const float* bf    = (const float*)d_in[12];

    const int N = in_sizes[0] / 128;
    const int E = in_sizes[1] / 2;
    const int G = out_size / 128;
    const int* rowp = ei;
    const int* colp = ei + E;
    float* out = (float*)d_out;

    char* w = (char*)d_ws;
    float*    bufA   = (float*)w;    w += (size_t)N * 128 * 4;
    float*    bufB   = (float*)w;    w += (size_t)N * 128 * 4;
    float*    dinv   = (float*)w;    w += (size_t)N * 4;
    unsigned* cnt    = (unsigned*)w; w += (size_t)N * 4;       // reused as cursor
    int*      off    = (int*)w;      w += (size_t)(N + 1) * 4;
    unsigned* bsum   = (unsigned*)w; w += 1024 * 4;
    int*      srow   = (int*)w;      w += (size_t)E * 4;
    float*    snorm  = (float*)w;    w += (size_t)E * 4;
    float*    sums   = (float*)w;    w += 256 * 4;
    unsigned* pooled = (unsigned*)w; w += (size_t)G * 128 * 4;

    const int nb = (N + 1023) / 1024;

    // ---- graph prep (once, reused by both layers) ----
    hipMemsetAsync(cnt, 0, (size_t)N * 4, stream);
    k_count<<<(E + 255) / 256, 256, 0, stream>>>(colp, cnt, E);
    k_dinv<<<(N + 255) / 256, 256, 0, stream>>>(cnt, dinv, N);
    k_chunk_sum<<<nb, 256, 0, stream>>>(cnt, N, bsum);
    k_scan_bsum<<<1, 64, 0, stream>>>(bsum, nb);
    k_scan_chunks<<<nb, 256, 0, stream>>>(cnt, N, bsum, off, E);
    hipMemcpyAsync(cnt, off, (size_t)N * 4, hipMemcpyDeviceToDevice, stream);  // cursor
    k_place<<<(E + 255) / 256, 256, 0, stream>>>(rowp, colp, dinv, (int*)cnt, srow, snorm, E);

    // ---- layer 1 ----
    k_gemm<<<(N + 63) / 64, 256, 0, stream>>>(x, W1, nullptr, bufA, N);
    hipMemsetAsync(sums, 0, 256 * 4, stream);
    k_agg2<<<1024, 256, 0, stream>>>(bufA, off, srow, snorm, dinv, b1, bufB, sums, N);
    k_bn<<<2048, 256, 0, stream>>>(bufB, sums, bn1w, bn1b, 1.0f / N, N * 128);

    // ---- layer 2 ----
    k_gemm<<<(N + 63) / 64, 256, 0, stream>>>(bufB, W2, nullptr, bufA, N);
    hipMemsetAsync(sums, 0, 256 * 4, stream);
    k_agg2<<<1024, 256, 0, stream>>>(bufA, off, srow, snorm, dinv, b2, bufB, sums, N);
    k_bn<<<2048, 256, 0, stream>>>(bufB, sums, bn2w, bn2b, 1.0f / N, N * 128);

    // ---- pooling ----
    k_pool_init<<<(G * 128 + 255) / 256, 256, 0, stream>>>(pooled, G * 128);
    k_pool2<<<(N + 127) / 128, 256, 0, stream>>>(bufB, batch, pooled, N);
    k_decode<<<(G * 128 + 255) / 256, 256, 0, stream>>>(pooled, G * 128);

    // ---- final GEMM ----
    k_gemm<<<(G + 63) / 64, 256, 0, stream>>>((const float*)pooled, Wf, bf, out, G);
}

// Round 4
// 507.295 us; speedup vs baseline: 5.9668x; 1.0701x over previous
//
#include <hip/hip_runtime.h>
#include <hip/hip_bf16.h>

#define EPSV 1e-5f
#define SLOPE 0.1f

typedef __attribute__((ext_vector_type(8))) unsigned short ushort8v;

static __device__ inline unsigned short f2bf(float f) {
    __hip_bfloat16 b = __float2bfloat16(f);
    return *reinterpret_cast<unsigned short*>(&b);
}
static __device__ inline float bf2f(unsigned short u) {
    return __uint_as_float(((unsigned)u) << 16);
}

// ---------------- degree ----------------
__global__ __launch_bounds__(256) void k_count(const int* __restrict__ col,
                                               unsigned* __restrict__ cnt, int E) {
    int e = blockIdx.x * 256 + threadIdx.x;
    if (e < E) atomicAdd(&cnt[col[e]], 1u);
}

__global__ __launch_bounds__(256) void k_dinv(const unsigned* __restrict__ cnt,
                                              float* __restrict__ dinv, int N) {
    int n = blockIdx.x * 256 + threadIdx.x;
    if (n < N) dinv[n] = rsqrtf((float)cnt[n] + 2.0f);
}

// ---------------- exclusive scan (3 kernels, 1024-elem chunks) ----------------
__global__ __launch_bounds__(256) void k_chunk_sum(const unsigned* __restrict__ cnt, int N,
                                                   unsigned* __restrict__ bsum) {
    __shared__ unsigned ls[256];
    int base = blockIdx.x * 1024;
    unsigned s = 0;
    for (int i = threadIdx.x; i < 1024; i += 256) {
        int idx = base + i;
        if (idx < N) s += cnt[idx];
    }
    ls[threadIdx.x] = s;
    __syncthreads();
    for (int st = 128; st > 0; st >>= 1) {
        if (threadIdx.x < st) ls[threadIdx.x] += ls[threadIdx.x + st];
        __syncthreads();
    }
    if (threadIdx.x == 0) bsum[blockIdx.x] = ls[0];
}

__global__ void k_scan_bsum(unsigned* __restrict__ bsum, int nb) {
    if (threadIdx.x == 0 && blockIdx.x == 0) {
        unsigned acc = 0;
        for (int i = 0; i < nb; i++) { unsigned v = bsum[i]; bsum[i] = acc; acc += v; }
    }
}

__global__ __launch_bounds__(256) void k_scan_chunks(const unsigned* __restrict__ cnt, int N,
                                                     const unsigned* __restrict__ bsum,
                                                     int* __restrict__ off, int E) {
    __shared__ unsigned ls[256];
    int base = blockIdx.x * 1024;
    unsigned v[4];
    unsigned s = 0;
#pragma unroll
    for (int j = 0; j < 4; j++) {
        int idx = base + threadIdx.x * 4 + j;
        v[j] = (idx < N) ? cnt[idx] : 0u;
        s += v[j];
    }
    ls[threadIdx.x] = s;
    __syncthreads();
    if (threadIdx.x == 0) {
        unsigned acc = bsum[blockIdx.x];
        for (int i = 0; i < 256; i++) { unsigned t = ls[i]; ls[i] = acc; acc += t; }
    }
    __syncthreads();
    unsigned acc = ls[threadIdx.x];
#pragma unroll
    for (int j = 0; j < 4; j++) {
        int idx = base + threadIdx.x * 4 + j;
        if (idx < N) off[idx] = (int)acc;
        acc += v[j];
    }
    if (base + threadIdx.x * 4 <= N - 1 && N - 1 < base + threadIdx.x * 4 + 4) off[N] = E;
}

// ---------------- counting-sort placement: (row, norm) packed, grouped by col ----------------
__global__ __launch_bounds__(256) void k_place(const int* __restrict__ row,
                                               const int* __restrict__ col,
                                               const float* __restrict__ dinv,
                                               int* __restrict__ cursor,
                                               int2* __restrict__ spack, int E) {
    int e = blockIdx.x * 256 + threadIdx.x;
    if (e >= E) return;
    int r = row[e], c = col[e];
    int pos = atomicAdd(&cursor[c], 1);
    spack[pos] = make_int2(r, __float_as_int(dinv[r] * dinv[c]));
}

// ---------------- GEMM: Y[N,128] = X[N,128] @ W[128,128] ----------------
// MODE 0: f32 in           -> bf16 out
// MODE 1: f32 in, BN+leaky -> bf16 out
// MODE 2: f32 in, +bias    -> f32 out
template <int MODE>
__global__ __launch_bounds__(256) void k_gemm_t(const float* __restrict__ X,
                                                const float* __restrict__ W,
                                                const float* __restrict__ sums, float invN,
                                                const float* __restrict__ bnw,
                                                const float* __restrict__ bnb,
                                                const float* __restrict__ bias,
                                                void* __restrict__ Yv, int N) {
    __shared__ float xs[64][132];
    __shared__ float sc[128], sb[128];
    const int tid = threadIdx.x;
    if (MODE == 1) {
        if (tid < 128) {
            float mu = sums[tid] * invN;
            float var = sums[128 + tid] * invN - mu * mu;
            float s = rsqrtf(var + EPSV) * bnw[tid];
            sc[tid] = s;
            sb[tid] = bnb[tid] - mu * s;
        }
        __syncthreads();
    }
    const int base = blockIdx.x * 64;
    for (int i = tid; i < 2048; i += 256) {
        int r = i >> 5, c4 = i & 31;
        int row = base + r; if (row >= N) row = N - 1;
        float4 v = ((const float4*)(X + (size_t)row * 128))[c4];
        if (MODE == 1) {
            int f = c4 * 4;
            v.x = fmaf(v.x, sc[f + 0], sb[f + 0]); v.x = v.x > 0.f ? v.x : SLOPE * v.x;
            v.y = fmaf(v.y, sc[f + 1], sb[f + 1]); v.y = v.y > 0.f ? v.y : SLOPE * v.y;
            v.z = fmaf(v.z, sc[f + 2], sb[f + 2]); v.z = v.z > 0.f ? v.z : SLOPE * v.z;
            v.w = fmaf(v.w, sc[f + 3], sb[f + 3]); v.w = v.w > 0.f ? v.w : SLOPE * v.w;
        }
        *(float4*)(&xs[r][c4 * 4]) = v;
    }
    __syncthreads();
    const int c0 = (tid & 31) * 4;
    const int rg = tid >> 5;
    float acc[8][4];
#pragma unroll
    for (int i = 0; i < 8; i++) { acc[i][0] = acc[i][1] = acc[i][2] = acc[i][3] = 0.f; }
    for (int k = 0; k < 128; k += 4) {
        float4 w0 = *(const float4*)(W + (size_t)(k + 0) * 128 + c0);
        float4 w1 = *(const float4*)(W + (size_t)(k + 1) * 128 + c0);
        float4 w2 = *(const float4*)(W + (size_t)(k + 2) * 128 + c0);
        float4 w3 = *(const float4*)(W + (size_t)(k + 3) * 128 + c0);
#pragma unroll
        for (int i = 0; i < 8; i++) {
            float4 a = *(const float4*)(&xs[rg + 8 * i][k]);
            acc[i][0] = fmaf(a.x, w0.x, fmaf(a.y, w1.x, fmaf(a.z, w2.x, fmaf(a.w, w3.x, acc[i][0]))));
            acc[i][1] = fmaf(a.x, w0.y, fmaf(a.y, w1.y, fmaf(a.z, w2.y, fmaf(a.w, w3.y, acc[i][1]))));
            acc[i][2] = fmaf(a.x, w0.z, fmaf(a.y, w1.z, fmaf(a.z, w2.z, fmaf(a.w, w3.z, acc[i][2]))));
            acc[i][3] = fmaf(a.x, w0.w, fmaf(a.y, w1.w, fmaf(a.z, w2.w, fmaf(a.w, w3.w, acc[i][3]))));
        }
    }
#pragma unroll
    for (int i = 0; i < 8; i++) {
        int row = base + rg + 8 * i;
        if (row < N) {
            if (MODE == 2) {
                float4 o = make_float4(acc[i][0] + bias[c0], acc[i][1] + bias[c0 + 1],
                                       acc[i][2] + bias[c0 + 2], acc[i][3] + bias[c0 + 3]);
                ((float4*)((float*)Yv + (size_t)row * 128))[tid & 31] = o;
            } else {
                ushort4 o;
                o.x = f2bf(acc[i][0]); o.y = f2bf(acc[i][1]);
                o.z = f2bf(acc[i][2]); o.w = f2bf(acc[i][3]);
                ((ushort4*)((unsigned short*)Yv + (size_t)row * 128))[tid & 31] = o;
            }
        }
    }
}

// ---------------- CSR aggregation (bf16 gather) + self-loop + bias + BN stats ----------------
// one wave per node; 4 edge-groups of 16 lanes; lane q covers features q*8..q*8+7
__global__ __launch_bounds__(256) void k_agg2(const unsigned short* __restrict__ xwh,
                                              const int* __restrict__ off,
                                              const int2* __restrict__ spack,
                                              const float* __restrict__ dinv,
                                              const float* __restrict__ bias,
                                              float* __restrict__ h,
                                              float* __restrict__ sums, int N) {
    __shared__ float ls1[128], ls2[128];
    const int tid = threadIdx.x;
    if (tid < 128) { ls1[tid] = 0.f; ls2[tid] = 0.f; }
    __syncthreads();

    const int lane = tid & 63;
    const int q = lane & 15;
    const int g = lane >> 4;  // 0..3
    const int wave = blockIdx.x * 4 + (tid >> 6);
    const int nW = gridDim.x * 4;

    float st1[8] = {0, 0, 0, 0, 0, 0, 0, 0};
    float st2[8] = {0, 0, 0, 0, 0, 0, 0, 0};
    float bj[8];
#pragma unroll
    for (int j = 0; j < 8; j++) bj[j] = bias[q * 8 + j];

    for (int n = wave; n < N; n += nW) {
        int s = off[n], e = off[n + 1];
        float a[8] = {0, 0, 0, 0, 0, 0, 0, 0};
        int i = s + g;
        if (i < e) {
            int2 p = spack[i];
            while (true) {
                int inext = i + 4;
                bool more = inext < e;
                int2 pn = make_int2(0, 0);
                if (more) pn = spack[inext];
                float nm = __int_as_float(p.y);
                ushort8v v = *(const ushort8v*)(xwh + (size_t)p.x * 128 + q * 8);
#pragma unroll
                for (int j = 0; j < 8; j++) a[j] = fmaf(nm, bf2f(v[j]), a[j]);
                if (!more) break;
                p = pn; i = inext;
            }
        }
        // reduce the 4 edge-groups
#pragma unroll
        for (int j = 0; j < 8; j++) {
            a[j] += __shfl_xor(a[j], 16);
            a[j] += __shfl_xor(a[j], 32);
        }
        if (lane < 16) {
            float dc = dinv[n];
            float sl = 2.f * dc * dc;
            ushort8v xv = *(const ushort8v*)(xwh + (size_t)n * 128 + q * 8);
            float o[8];
#pragma unroll
            for (int j = 0; j < 8; j++) {
                o[j] = a[j] + sl * bf2f(xv[j]) + bj[j];
                st1[j] += o[j];
                st2[j] += o[j] * o[j];
            }
            float4* hp = (float4*)(h + (size_t)n * 128 + q * 8);
            hp[0] = make_float4(o[0], o[1], o[2], o[3]);
            hp[1] = make_float4(o[4], o[5], o[6], o[7]);
        }
    }
    if (lane < 16) {
#pragma unroll
        for (int j = 0; j < 8; j++) {
            atomicAdd(&ls1[q * 8 + j], st1[j]);
            atomicAdd(&ls2[q * 8 + j], st2[j]);
        }
    }
    __syncthreads();
    if (tid < 128) {
        atomicAdd(&sums[tid], ls1[tid]);
        atomicAdd(&sums[128 + tid], ls2[tid]);
    }
}

// ---------------- pooling with fused BN2 + leaky ----------------
__global__ __launch_bounds__(256) void k_pool_init(unsigned* __restrict__ p, int total) {
    int i = blockIdx.x * 256 + threadIdx.x;
    if (i < total) p[i] = 0x007FFFFFu;  // encoded -inf
}

__device__ inline unsigned enc_f(float x) {
    unsigned u = __float_as_uint(x);
    return (u & 0x80000000u) ? ~u : (u | 0x80000000u);
}

__global__ __launch_bounds__(256) void k_pool2(const float* __restrict__ h,
                                               const int* __restrict__ batch,
                                               const float* __restrict__ sums, float invN,
                                               const float* __restrict__ bnw,
                                               const float* __restrict__ bnb,
                                               unsigned* __restrict__ pooled, int N) {
    const int f = threadIdx.x & 127;
    const int half = threadIdx.x >> 7;
    float mu = sums[f] * invN;
    float var = sums[128 + f] * invN - mu * mu;
    float scale = rsqrtf(var + EPSV) * bnw[f];
    float bias = bnb[f] - mu * scale;
    const int base = blockIdx.x * 128;
    const int end = min(base + 128, N);
    float m = -__builtin_inff();
    int g = -1;
    for (int n = base + half; n < end; n += 2) {
        int bg = batch[n];
        if (bg != g) {
            if (g >= 0) atomicMax(&pooled[(size_t)g * 128 + f], enc_f(m));
            g = bg;
            m = -__builtin_inff();
        }
        float v = fmaf(h[(size_t)n * 128 + f], scale, bias);
        v = v > 0.f ? v : SLOPE * v;
        m = fmaxf(m, v);
    }
    if (g >= 0) atomicMax(&pooled[(size_t)g * 128 + f], enc_f(m));
}

__global__ __launch_bounds__(256) void k_decode(unsigned* __restrict__ p, int total) {
    int i = blockIdx.x * 256 + threadIdx.x;
    if (i >= total) return;
    unsigned u = p[i];
    float v;
    if (u == 0x007FFFFFu) v = 0.f;  // empty graph (-inf) -> 0
    else if (u & 0x80000000u) v = __uint_as_float(u & 0x7FFFFFFFu);
    else v = __uint_as_float(~u);
    p[i] = __float_as_uint(v);
}

extern "C" void kernel_launch(void* const* d_in, const int* in_sizes, int n_in,
                              void* d_out, int out_size, void* d_ws, size_t ws_size,
                              hipStream_t stream) {
    const float* x     = (const float*)d_in[0];
    const int*   ei    = (const int*)d_in[1];
    const int*   batch = (const int*)d_in[2];
    const float* W1    = (const float*)d_in[3];
    const float* b1    = (const float*)d_in[4];
    const float* bn1w  = (const float*)d_in[5];
    const float* bn1b  = (const float*)d_in[6];
    const float* W2    = (const float*)d_in[7];
    const float* b2    = (const float*)d_in[8];
    const float* bn2w  = (const float*)d_in[9];
    const float* bn2b  = (const float*)d_in[10];
    const float* Wf    = (const float*)d_in[11];
    const float* bf    = (const float*)d_in[12];

    const int N = in_sizes[0] / 128;
    const int E = in_sizes[1] / 2;
    const int G = out_size / 128;
    const int* rowp = ei;
    const int* colp = ei + E;
    float* out = (float*)d_out;
    const float invN = 1.0f / N;

    char* w = (char*)d_ws;
    unsigned short* bufAh = (unsigned short*)w; w += (size_t)N * 128 * 2;  // bf16 xw
    float*    bufB   = (float*)w;    w += (size_t)N * 128 * 4;             // f32 h
    float*    dinv   = (float*)w;    w += (size_t)N * 4;
    unsigned* cnt    = (unsigned*)w; w += (size_t)N * 4;                   // reused as cursor
    int*      off    = (int*)w;      w += (size_t)(N + 1) * 4;
    unsigned* bsum   = (unsigned*)w; w += 1024 * 4;
    int2*     spack  = (int2*)w;     w += (size_t)E * 8;
    float*    sums   = (float*)w;    w += 512 * 4;                         // sums1 | sums2
    unsigned* pooled = (unsigned*)w; w += (size_t)G * 128 * 4;

    float* sums1 = sums;
    float* sums2 = sums + 256;
    const int nb = (N + 1023) / 1024;

    // ---- graph prep (once, reused by both layers) ----
    hipMemsetAsync(cnt, 0, (size_t)N * 4, stream);
    hipMemsetAsync(sums, 0, 512 * 4, stream);
    k_count<<<(E + 255) / 256, 256, 0, stream>>>(colp, cnt, E);
    k_dinv<<<(N + 255) / 256, 256, 0, stream>>>(cnt, dinv, N);
    k_chunk_sum<<<nb, 256, 0, stream>>>(cnt, N, bsum);
    k_scan_bsum<<<1, 64, 0, stream>>>(bsum, nb);
    k_scan_chunks<<<nb, 256, 0, stream>>>(cnt, N, bsum, off, E);
    hipMemcpyAsync(cnt, off, (size_t)N * 4, hipMemcpyDeviceToDevice, stream);  // cursor
    k_place<<<(E + 255) / 256, 256, 0, stream>>>(rowp, colp, dinv, (int*)cnt, spack, E);

    // ---- layer 1 ----
    k_gemm_t<0><<<(N + 63) / 64, 256, 0, stream>>>(x, W1, nullptr, 0.f, nullptr, nullptr,
                                                   nullptr, bufAh, N);
    k_agg2<<<2048, 256, 0, stream>>>(bufAh, off, spack, dinv, b1, bufB, sums1, N);

    // ---- layer 2 (BN1 fused into GEMM staging) ----
    k_gemm_t<1><<<(N + 63) / 64, 256, 0, stream>>>(bufB, W2, sums1, invN, bn1w, bn1b,
                                                   nullptr, bufAh, N);
    k_agg2<<<2048, 256, 0, stream>>>(bufAh, off, spack, dinv, b2, bufB, sums2, N);

    // ---- pooling (BN2 fused) ----
    k_pool_init<<<(G * 128 + 255) / 256, 256, 0, stream>>>(pooled, G * 128);
    k_pool2<<<(N + 127) / 128, 256, 0, stream>>>(bufB, batch, sums2, invN, bn2w, bn2b,
                                                 pooled, N);
    k_decode<<<(G * 128 + 255) / 256, 256, 0, stream>>>(pooled, G * 128);

    // ---- final GEMM ----
    k_gemm_t<2><<<(G + 63) / 64, 256, 0, stream>>>((const float*)pooled, Wf, nullptr, 0.f,
                                                   nullptr, nullptr, bf, out, G);
}